// Round 11
// baseline (556.488 us; speedup 1.0000x reference)
//
#include <hip/hip_runtime.h>
#include <math.h>

#define NN 20000
#define NE 640000
#define GDIM 50
#define LAYERS 6
#define NGRAPH 64
#define TBL 2048
#define DMAXF 12.8f
#define G2_PAD 136   // LDS row stride in shorts (128 + 8 pad)
#define CK 8         // edge pipeline chunk

typedef __attribute__((ext_vector_type(8))) short short8;
typedef __attribute__((ext_vector_type(4))) float floatx4;

__device__ __forceinline__ float sspf(float x) {
    float sp = (x > 30.0f) ? x : log1pf(expf(x));
    return sp - 0.69314718055994530942f;
}

__device__ __forceinline__ unsigned short f2bs(float f) {
    union { float f; unsigned int i; } u; u.f = f;
    unsigned int r = u.i + 0x7fffu + ((u.i >> 16) & 1u);
    return (unsigned short)(r >> 16);
}

__device__ __forceinline__ float bs2f(unsigned int bits16) {
    union { unsigned int i; float f; } u; u.i = bits16 << 16;
    return u.f;
}

__device__ __forceinline__ short8 pack_bf16x8(float4 a, float4 b) {
    short8 o;
    o[0] = (short)f2bs(a.x); o[1] = (short)f2bs(a.y);
    o[2] = (short)f2bs(a.z); o[3] = (short)f2bs(a.w);
    o[4] = (short)f2bs(b.x); o[5] = (short)f2bs(b.y);
    o[6] = (short)f2bs(b.z); o[7] = (short)f2bs(b.w);
    return o;
}

// ---- merged prep: 26 weight transposes + deg=0 + out=0 + gaussian table +
//      h_init + per-graph inverse counts ----
struct WArgs { const float* s[26]; unsigned short* d[26]; };
#define PREP_WBLK 416            // 26 matrices x 16 tiles
__global__ void prep_a(WArgs a, int* __restrict__ deg, float* __restrict__ out,
                       float* __restrict__ A_tab, const int* __restrict__ z,
                       const float* __restrict__ emb, float* __restrict__ h,
                       const int* __restrict__ batch, float* __restrict__ inv_cnt) {
    __shared__ float tile[32][33];
    int b = blockIdx.x;
    if (b < PREP_WBLK) {
        int mz = b >> 4, sub = b & 15;
        int bx = (sub & 3) * 32, by = (sub >> 2) * 32;
        const float* Wm = a.s[mz];
        unsigned short* Wo = a.d[mz];
        int tx = threadIdx.x & 31, ty = threadIdx.x >> 5;
        for (int r = ty; r < 32; r += 8) tile[r][tx] = Wm[(by + r) * 128 + bx + tx];
        __syncthreads();
        for (int r = ty; r < 32; r += 8) Wo[(bx + r) * 128 + by + tx] = f2bs(tile[tx][r]);
        return;
    }
    int idx = (b - PREP_WBLK) * 256 + threadIdx.x;
    if (idx < NN) { deg[idx] = 0; return; }
    idx -= NN;
    if (idx < NGRAPH * 128) { out[idx] = 0.f; return; }
    idx -= NGRAPH * 128;
    if (idx < (TBL + 2) * GDIM) {
        int i = idx / GDIM, g = idx % GDIM;
        float v = 0.0f;
        if (i <= TBL) {
            float d = (float)i * (DMAXF / (float)TBL);
            float step = 10.0f / 49.0f;
            float off = (float)g * step;
            float coeff = -0.5f / (step * step);
            float dd = d - off;
            v = expf(coeff * dd * dd);
        }
        A_tab[idx] = v;
        return;
    }
    idx -= (TBL + 2) * GDIM;
    if (idx < NN * 32) {
        int n = idx >> 5, q = idx & 31;
        ((float4*)h)[n * 32 + q] = ((const float4*)emb)[(size_t)z[n] * 32 + q];
        return;
    }
    idx -= NN * 32;
    if (idx < NGRAPH) {
        int lo = 0, hi = NN;
        while (lo < hi) { int m = (lo + hi) >> 1; if (batch[m] < idx) lo = m + 1; else hi = m; }
        int lo2 = lo, hi2 = NN;
        while (lo2 < hi2) { int m = (lo2 + hi2) >> 1; if (batch[m] < idx + 1) lo2 = m + 1; else hi2 = m; }
        int cnt = lo2 - lo;
        inv_cnt[idx] = 1.0f / (float)(cnt > 0 ? cnt : 1);
    }
}

__global__ void deg_hist(const int* __restrict__ dst, int* __restrict__ deg) {
    int j = blockIdx.x * blockDim.x + threadIdx.x;
    if (j >= NE) return;
    atomicAdd(&deg[dst[j]], 1);
}

// hierarchical scan: local 256-scan + blocksums
__global__ void scan_a(const int* __restrict__ deg, int* __restrict__ row_ptr,
                       int* __restrict__ bsum) {
    __shared__ int sh[256];
    int b = blockIdx.x, t = threadIdx.x;
    int i = b * 256 + t;
    int v = (i < NN) ? deg[i] : 0;
    int x = v;
    sh[t] = x;
    __syncthreads();
    for (int off = 1; off < 256; off <<= 1) {
        int u = (t >= off) ? sh[t - off] : 0;
        __syncthreads();
        x += u;
        sh[t] = x;
        __syncthreads();
    }
    if (i <= NN) row_ptr[i] = x - v;   // local exclusive
    if (t == 255) bsum[b] = x;
}

// add block-prefix offsets; init cursor
__global__ void scan_b(const int* __restrict__ bsum, int* __restrict__ row_ptr,
                       int* __restrict__ cursor) {
    __shared__ int spref;
    int b = blockIdx.x, t = threadIdx.x;
    if (t < 64) {
        int s = 0;
        if (t < b) s += bsum[t];
        if (t + 64 < b) s += bsum[t + 64];
        for (int off = 32; off; off >>= 1) s += __shfl_down(s, off);
        if (t == 0) spref = s;
    }
    __syncthreads();
    int prefix = spref;
    int i = b * 256 + t;
    if (i < NN) {
        int v = row_ptr[i] + prefix;
        row_ptr[i] = v;
        cursor[i] = v;
    }
    if (b == 0 && t == 0) row_ptr[NN] = NE;
}

// CSR entry: int2{ (i0<<15)|src , bits(f) }   (cutoff C folded into table)
__global__ void csr_fill(const float* __restrict__ pos, const int* __restrict__ src,
                         const int* __restrict__ dst, int* __restrict__ cursor,
                         int2* __restrict__ csr) {
    int j = blockIdx.x * blockDim.x + threadIdx.x;
    if (j >= NE) return;
    int s = src[j], tno = dst[j];
    float dx = pos[3*s+0] - pos[3*tno+0];
    float dy = pos[3*s+1] - pos[3*tno+1];
    float dz = pos[3*s+2] - pos[3*tno+2];
    float d = sqrtf(dx*dx + dy*dy + dz*dz);
    float u = d * ((float)TBL / DMAXF);
    u = fminf(u, (float)(TBL + 1));
    int i0 = (int)u; if (i0 > TBL) i0 = TBL;
    float f = u - (float)i0;
    int p = atomicAdd(&cursor[tno], 1);
    csr[p] = make_int2((i0 << 15) | s, __float_as_int(f));
}

// fp32 tiled GEMM for the K=50 table stage only, batched over gridDim.y
template <int K>
__launch_bounds__(256, 2)
__global__ void gemm_t(const float* __restrict__ A, const float* __restrict__ W,
                       const float* __restrict__ bias, float* __restrict__ Y, int M,
                       int act, int aStride, int wStride, int bStride, int yStride) {
    constexpr int KP = (K + 3) & ~3;
    __shared__ __align__(16) float Ws[KP * 128];
    __shared__ __align__(16) float As[32 * KP];
    int l = blockIdx.y;
    A += (size_t)l * aStride;
    W += (size_t)l * wStride;
    if (bias) bias += (size_t)l * bStride;
    Y += (size_t)l * yStride;
    int t = threadIdx.x;
    int row0 = blockIdx.x * 32;
    for (int i = t; i < KP * 128; i += 256) Ws[i] = (i < K * 128) ? W[i] : 0.0f;
    for (int i = t; i < 32 * KP; i += 256) {
        int r = i / KP, k = i % KP;
        float v = 0.f;
        if (k < K && row0 + r < M) v = A[(size_t)(row0 + r) * K + k];
        As[r * KP + k] = v;
    }
    __syncthreads();
    int tx = t & 31, ty = t >> 5;
    int c0 = tx * 4, r0 = ty * 4;
    float acc[4][4] = {{0.f}};
    #pragma unroll 4
    for (int k = 0; k < KP; k += 4) {
        float4 a0 = *(const float4*)&As[(r0 + 0) * KP + k];
        float4 a1 = *(const float4*)&As[(r0 + 1) * KP + k];
        float4 a2 = *(const float4*)&As[(r0 + 2) * KP + k];
        float4 a3 = *(const float4*)&As[(r0 + 3) * KP + k];
        float4 w0 = *(const float4*)&Ws[(k + 0) * 128 + c0];
        float4 w1 = *(const float4*)&Ws[(k + 1) * 128 + c0];
        float4 w2 = *(const float4*)&Ws[(k + 2) * 128 + c0];
        float4 w3 = *(const float4*)&Ws[(k + 3) * 128 + c0];
        float av[4][4] = {{a0.x,a0.y,a0.z,a0.w},{a1.x,a1.y,a1.z,a1.w},
                          {a2.x,a2.y,a2.z,a2.w},{a3.x,a3.y,a3.z,a3.w}};
        float wv[4][4] = {{w0.x,w0.y,w0.z,w0.w},{w1.x,w1.y,w1.z,w1.w},
                          {w2.x,w2.y,w2.z,w2.w},{w3.x,w3.y,w3.z,w3.w}};
        #pragma unroll
        for (int i = 0; i < 4; i++)
            #pragma unroll
            for (int j = 0; j < 4; j++)
                #pragma unroll
                for (int q = 0; q < 4; q++)
                    acc[i][j] += av[i][q] * wv[q][j];
    }
    float b0 = 0.f, b1 = 0.f, b2 = 0.f, b3 = 0.f;
    if (bias) { b0 = bias[c0]; b1 = bias[c0+1]; b2 = bias[c0+2]; b3 = bias[c0+3]; }
    #pragma unroll
    for (int i = 0; i < 4; i++) {
        int r = row0 + r0 + i;
        if (r >= M) break;
        float4 v;
        v.x = acc[i][0] + b0; v.y = acc[i][1] + b1; v.z = acc[i][2] + b2; v.w = acc[i][3] + b3;
        if (act == 1) { v.x = sspf(v.x); v.y = sspf(v.y); v.z = sspf(v.z); v.w = sspf(v.w); }
        *(float4*)&Y[(size_t)r * 128 + c0] = v;
    }
}

// merged col-split MFMA GEMM: y<6 -> table layer y; y==6 -> layer-0 xfb job
__launch_bounds__(256)
__global__ void gemm_cs2(const float* __restrict__ A1, const unsigned short* __restrict__ W1t,
                         const float* __restrict__ bias1, float* __restrict__ Y1, int M1,
                         const float* __restrict__ A2, const unsigned short* __restrict__ W2t,
                         unsigned short* __restrict__ Yb2, int M2) {
    int y = blockIdx.y;
    const float* A; const unsigned short* Wt; const float* bias;
    float* Yf; unsigned short* Yb; int M;
    if (y < LAYERS) {
        M = M1;
        A = A1 + (size_t)y * M1 * 128;
        Wt = W1t + (size_t)y * 16384;
        bias = bias1 + (size_t)y * 128;
        Yf = Y1 + (size_t)y * M1 * 128;
        Yb = nullptr;
    } else {
        M = M2; A = A2; Wt = W2t; bias = nullptr; Yf = nullptr; Yb = Yb2;
    }
    int wv = threadIdx.x >> 6, lane = threadIdx.x & 63;
    int row0 = blockIdx.x * 32;
    if (row0 >= M) return;
    int lm = lane & 15, lk = (lane >> 4) * 8, orow = (lane >> 4) * 4;
    int r0 = row0 + lm;      r0 = (r0 < M) ? r0 : M - 1;
    int r1 = row0 + 16 + lm; r1 = (r1 < M) ? r1 : M - 1;
    const float* Ap0 = A + (size_t)r0 * 128;
    const float* Ap1 = A + (size_t)r1 * 128;
    short8 af0[4], af1[4];
    #pragma unroll
    for (int kq = 0; kq < 4; kq++) {
        af0[kq] = pack_bf16x8(*(const float4*)(Ap0 + kq * 32 + lk),
                              *(const float4*)(Ap0 + kq * 32 + lk + 4));
        af1[kq] = pack_bf16x8(*(const float4*)(Ap1 + kq * 32 + lk),
                              *(const float4*)(Ap1 + kq * 32 + lk + 4));
    }
    floatx4 acc[2][2];
    #pragma unroll
    for (int i = 0; i < 2; i++)
        #pragma unroll
        for (int j = 0; j < 2; j++) acc[i][j] = (floatx4){0, 0, 0, 0};
    const unsigned short* Wp = Wt + (size_t)(wv * 32) * 128;
    #pragma unroll
    for (int kq = 0; kq < 4; kq++) {
        #pragma unroll
        for (int ct = 0; ct < 2; ct++) {
            short8 bf = *(const short8*)(Wp + (size_t)(ct * 16 + lm) * 128 + kq * 32 + lk);
            acc[0][ct] = __builtin_amdgcn_mfma_f32_16x16x32_bf16(af0[kq], bf, acc[0][ct], 0, 0, 0);
            acc[1][ct] = __builtin_amdgcn_mfma_f32_16x16x32_bf16(af1[kq], bf, acc[1][ct], 0, 0, 0);
        }
    }
    #pragma unroll
    for (int tt = 0; tt < 2; tt++) {
        #pragma unroll
        for (int ct = 0; ct < 2; ct++) {
            int c = wv * 32 + ct * 16 + lm;
            float b = bias ? bias[c] : 0.f;
            #pragma unroll
            for (int r = 0; r < 4; r++) {
                int rr = row0 + tt * 16 + orow + r;
                if (rr >= M) continue;
                float v = acc[tt][ct][r] + b;
                if (Yf) Yf[(size_t)rr * 128 + c] = v;
                if (Yb) Yb[(size_t)rr * 128 + c] = f2bs(v);
            }
        }
    }
}

// fused triple GEMM, 16 rows/block, col-split waves; A input is bf16 (from edge_agg)
__launch_bounds__(256)
__global__ void gemm3(const unsigned short* __restrict__ aggb,
                      const unsigned short* __restrict__ W2t, const float* __restrict__ b2,
                      const unsigned short* __restrict__ W3t, const float* __restrict__ b3,
                      const float* __restrict__ resid, float* __restrict__ Yf,
                      const unsigned short* __restrict__ W1nt, unsigned short* __restrict__ xfb) {
    __shared__ unsigned short Ls[16 * G2_PAD];
    int wv = threadIdx.x >> 6, lane = threadIdx.x & 63;
    int row0 = blockIdx.x * 16;
    int lm = lane & 15, lk = (lane >> 4) * 8, orow = (lane >> 4) * 4;
    int cw = wv * 32;
    // prefetch residual rows early (consumed at phase-2 epilogue)
    float rpre[2][4];
    #pragma unroll
    for (int ct = 0; ct < 2; ct++)
        #pragma unroll
        for (int r = 0; r < 4; r++)
            rpre[ct][r] = resid[(size_t)(row0 + orow + r) * 128 + cw + ct * 16 + lm];
    // ---- phase 1: t1 = ssp(aggb @ W2t^T + b2) -> LDS ----
    {
        const unsigned short* Ap = aggb + (size_t)(row0 + lm) * 128;
        short8 af[4];
        #pragma unroll
        for (int kq = 0; kq < 4; kq++)
            af[kq] = *(const short8*)(Ap + kq * 32 + lk);
        floatx4 acc[2];
        acc[0] = (floatx4){0, 0, 0, 0}; acc[1] = (floatx4){0, 0, 0, 0};
        const unsigned short* Wp = W2t + (size_t)cw * 128;
        #pragma unroll
        for (int kq = 0; kq < 4; kq++) {
            #pragma unroll
            for (int ct = 0; ct < 2; ct++) {
                short8 bf = *(const short8*)(Wp + (size_t)(ct * 16 + lm) * 128 + kq * 32 + lk);
                acc[ct] = __builtin_amdgcn_mfma_f32_16x16x32_bf16(af[kq], bf, acc[ct], 0, 0, 0);
            }
        }
        #pragma unroll
        for (int ct = 0; ct < 2; ct++) {
            int c = cw + ct * 16 + lm;
            float b = b2[c];
            #pragma unroll
            for (int r = 0; r < 4; r++)
                Ls[(orow + r) * G2_PAD + c] = f2bs(sspf(acc[ct][r] + b));
        }
    }
    __syncthreads();
    // ---- phase 2: h_new = t1 @ W3t^T + b3 + resid -> Yf ----
    float vout[2][4];
    {
        short8 a2[4];
        #pragma unroll
        for (int kq = 0; kq < 4; kq++)
            a2[kq] = *(const short8*)&Ls[lm * G2_PAD + kq * 32 + lk];
        floatx4 acc[2];
        acc[0] = (floatx4){0, 0, 0, 0}; acc[1] = (floatx4){0, 0, 0, 0};
        const unsigned short* Wp = W3t + (size_t)cw * 128;
        #pragma unroll
        for (int kq = 0; kq < 4; kq++) {
            #pragma unroll
            for (int ct = 0; ct < 2; ct++) {
                short8 bf = *(const short8*)(Wp + (size_t)(ct * 16 + lm) * 128 + kq * 32 + lk);
                acc[ct] = __builtin_amdgcn_mfma_f32_16x16x32_bf16(a2[kq], bf, acc[ct], 0, 0, 0);
            }
        }
        #pragma unroll
        for (int ct = 0; ct < 2; ct++) {
            int c = cw + ct * 16 + lm;
            float b = b3[c];
            #pragma unroll
            for (int r = 0; r < 4; r++) {
                int rr = row0 + orow + r;
                float v = acc[ct][r] + b + rpre[ct][r];
                Yf[(size_t)rr * 128 + c] = v;
                vout[ct][r] = v;
            }
        }
    }
    if (!W1nt) return;
    __syncthreads();
    #pragma unroll
    for (int ct = 0; ct < 2; ct++) {
        int c = cw + ct * 16 + lm;
        #pragma unroll
        for (int r = 0; r < 4; r++)
            Ls[(orow + r) * G2_PAD + c] = f2bs(vout[ct][r]);
    }
    __syncthreads();
    // ---- phase 3: xfb = bf16(h_new @ W1nt^T) ----
    {
        short8 a3[4];
        #pragma unroll
        for (int kq = 0; kq < 4; kq++)
            a3[kq] = *(const short8*)&Ls[lm * G2_PAD + kq * 32 + lk];
        floatx4 acc[2];
        acc[0] = (floatx4){0, 0, 0, 0}; acc[1] = (floatx4){0, 0, 0, 0};
        const unsigned short* Wp = W1nt + (size_t)cw * 128;
        #pragma unroll
        for (int kq = 0; kq < 4; kq++) {
            #pragma unroll
            for (int ct = 0; ct < 2; ct++) {
                short8 bf = *(const short8*)(Wp + (size_t)(ct * 16 + lm) * 128 + kq * 32 + lk);
                acc[ct] = __builtin_amdgcn_mfma_f32_16x16x32_bf16(a3[kq], bf, acc[ct], 0, 0, 0);
            }
        }
        #pragma unroll
        for (int ct = 0; ct < 2; ct++) {
            int c = cw + ct * 16 + lm;
            #pragma unroll
            for (int r = 0; r < 4; r++)
                xfb[(size_t)(row0 + orow + r) * 128 + c] = f2bs(acc[ct][r]);
        }
    }
}

// head: out[g] += mean-scaled ssp(h @ out1 + b1) @ out2 + b2  (fused readout)
__launch_bounds__(256)
__global__ void gemm3h(const float* __restrict__ A,
                       const unsigned short* __restrict__ W2t, const float* __restrict__ b2,
                       const unsigned short* __restrict__ W3t, const float* __restrict__ b3,
                       const int* __restrict__ batch, const float* __restrict__ inv_cnt,
                       float* __restrict__ out) {
    __shared__ unsigned short Ls[16 * G2_PAD];
    int wv = threadIdx.x >> 6, lane = threadIdx.x & 63;
    int row0 = blockIdx.x * 16;
    int lm = lane & 15, lk = (lane >> 4) * 8, orow = (lane >> 4) * 4;
    int cw = wv * 32;
    {
        const float* Ap = A + (size_t)(row0 + lm) * 128;
        short8 af[4];
        #pragma unroll
        for (int kq = 0; kq < 4; kq++)
            af[kq] = pack_bf16x8(*(const float4*)(Ap + kq * 32 + lk),
                                 *(const float4*)(Ap + kq * 32 + lk + 4));
        floatx4 acc[2];
        acc[0] = (floatx4){0, 0, 0, 0}; acc[1] = (floatx4){0, 0, 0, 0};
        const unsigned short* Wp = W2t + (size_t)cw * 128;
        #pragma unroll
        for (int kq = 0; kq < 4; kq++) {
            #pragma unroll
            for (int ct = 0; ct < 2; ct++) {
                short8 bf = *(const short8*)(Wp + (size_t)(ct * 16 + lm) * 128 + kq * 32 + lk);
                acc[ct] = __builtin_amdgcn_mfma_f32_16x16x32_bf16(af[kq], bf, acc[ct], 0, 0, 0);
            }
        }
        #pragma unroll
        for (int ct = 0; ct < 2; ct++) {
            int c = cw + ct * 16 + lm;
            float b = b2[c];
            #pragma unroll
            for (int r = 0; r < 4; r++)
                Ls[(orow + r) * G2_PAD + c] = f2bs(sspf(acc[ct][r] + b));
        }
    }
    __syncthreads();
    float vout[2][4];
    {
        short8 a2[4];
        #pragma unroll
        for (int kq = 0; kq < 4; kq++)
            a2[kq] = *(const short8*)&Ls[lm * G2_PAD + kq * 32 + lk];
        floatx4 acc[2];
        acc[0] = (floatx4){0, 0, 0, 0}; acc[1] = (floatx4){0, 0, 0, 0};
        const unsigned short* Wp = W3t + (size_t)cw * 128;
        #pragma unroll
        for (int kq = 0; kq < 4; kq++) {
            #pragma unroll
            for (int ct = 0; ct < 2; ct++) {
                short8 bf = *(const short8*)(Wp + (size_t)(ct * 16 + lm) * 128 + kq * 32 + lk);
                acc[ct] = __builtin_amdgcn_mfma_f32_16x16x32_bf16(a2[kq], bf, acc[ct], 0, 0, 0);
            }
        }
        #pragma unroll
        for (int ct = 0; ct < 2; ct++) {
            int c = cw + ct * 16 + lm;
            float b = b3[c];
            #pragma unroll
            for (int r = 0; r < 4; r++)
                vout[ct][r] = acc[ct][r] + b;
        }
    }
    // fused mean readout
    int g0  = __builtin_amdgcn_readfirstlane(batch[row0]);
    int g15 = __builtin_amdgcn_readfirstlane(batch[row0 + 15]);
    if (g0 == g15) {
        float inv = inv_cnt[g0];
        #pragma unroll
        for (int ct = 0; ct < 2; ct++) {
            float s = vout[ct][0] + vout[ct][1] + vout[ct][2] + vout[ct][3];
            s += __shfl_xor(s, 16);
            s += __shfl_xor(s, 32);
            if (lane < 16)
                atomicAdd(&out[g0 * 128 + cw + ct * 16 + lm], s * inv);
        }
    } else {
        #pragma unroll
        for (int ct = 0; ct < 2; ct++) {
            int c = cw + ct * 16 + lm;
            #pragma unroll
            for (int r = 0; r < 4; r++) {
                int g = batch[row0 + orow + r];
                atomicAdd(&out[g * 128 + c], vout[ct][r] * inv_cnt[g]);
            }
        }
    }
}

// fold cutoff C(d) into table; one uint per channel: (dW<<16)|W
__global__ void tquant(const float* __restrict__ T, unsigned int* __restrict__ Tb) {
    int idx = blockIdx.x * blockDim.x + threadIdx.x;
    const int total = LAYERS * (TBL + 1) * 128;
    if (idx >= total) return;
    int c = idx & 127;
    int li = idx >> 7;
    int i = li % (TBL + 1);
    int l = li / (TBL + 1);
    float d0 = (float)i * (DMAXF / (float)TBL);
    float d1 = (float)(i + 1) * (DMAXF / (float)TBL);
    float C0 = 0.5f * (cosf(d0 * 0.31415926535897931f) + 1.0f);
    float C1 = 0.5f * (cosf(d1 * 0.31415926535897931f) + 1.0f);
    const float* row = T + ((size_t)l * (TBL + 2) + i) * 128 + c;
    float w = row[0] * C0;
    float nw = row[128] * C1;
    Tb[idx] = ((unsigned)f2bs(nw - w) << 16) | f2bs(w);
}

// 2 waves per node; scalar CSR loads; 2-deep software-pipelined 8-edge chunks
__launch_bounds__(256)
__global__ void edge_agg(const int* __restrict__ row_ptr, const int2* __restrict__ csr,
                         const unsigned int* __restrict__ Tb,
                         const unsigned short* __restrict__ xfb,
                         unsigned short* __restrict__ aggb) {
    int wv = __builtin_amdgcn_readfirstlane(threadIdx.x >> 6);
    int lane = threadIdx.x & 63;
    int n = blockIdx.x * 2 + (wv >> 1);
    int c = (wv & 1) * 64 + lane;
    int e0 = row_ptr[n], e1 = row_ptr[n + 1];
    float ax = 0.f;

    unsigned pxA[CK], pxB[CK];
    float ffA[CK], ffB[CK];
    unsigned twA[CK], twB[CK];
    unsigned short xvA[CK], xvB[CK];

    auto loadS = [&](unsigned* px, float* ff, int base) {
        #pragma unroll
        for (int q = 0; q < CK; q++) {
            int2 ed = csr[base + q];
            px[q] = (unsigned)__builtin_amdgcn_readfirstlane(ed.x);
            ff[q] = __int_as_float(__builtin_amdgcn_readfirstlane(ed.y));
        }
    };
    auto loadV = [&](unsigned* tw, unsigned short* xv, const unsigned* px) {
        #pragma unroll
        for (int q = 0; q < CK; q++) {
            tw[q] = Tb[(px[q] >> 15) * 128 + c];
            xv[q] = xfb[(size_t)(px[q] & 0x7fffu) * 128 + c];
        }
    };
    auto fmaC = [&](const unsigned* tw, const unsigned short* xv, const float* ff) {
        #pragma unroll
        for (int q = 0; q < CK; q++) {
            float w = bs2f(tw[q] & 0xffffu), dw = bs2f(tw[q] >> 16);
            float x = bs2f((unsigned)xv[q]);
            ax = fmaf(x, fmaf(ff[q], dw, w), ax);
        }
    };

    int nfull = (e1 - e0) / CK;
    if (nfull > 0) {
        loadS(pxA, ffA, e0);
        loadV(twA, xvA, pxA);
        if (nfull > 1) loadS(pxB, ffB, e0 + CK);
        int it = 0;
        for (; it + 2 <= nfull; it += 2) {
            loadV(twB, xvB, pxB);                           // chunk it+1 vloads
            fmaC(twA, xvA, ffA);                            // chunk it
            if (it + 2 < nfull) {
                loadS(pxA, ffA, e0 + (it + 2) * CK);
                loadV(twA, xvA, pxA);                       // chunk it+2 vloads
            }
            fmaC(twB, xvB, ffB);                            // chunk it+1
            if (it + 3 < nfull) loadS(pxB, ffB, e0 + (it + 3) * CK);
        }
        if (it < nfull) fmaC(twA, xvA, ffA);                // odd leftover chunk
    }
    for (int e = e0 + nfull * CK; e < e1; e++) {
        int2 ed = csr[e];
        unsigned px = (unsigned)__builtin_amdgcn_readfirstlane(ed.x);
        float f = __int_as_float(__builtin_amdgcn_readfirstlane(ed.y));
        unsigned tw = Tb[(px >> 15) * 128 + c];
        unsigned short xv = xfb[(size_t)(px & 0x7fffu) * 128 + c];
        float w = bs2f(tw & 0xffffu), dw = bs2f(tw >> 16);
        float x = bs2f((unsigned)xv);
        ax = fmaf(x, fmaf(f, dw, w), ax);
    }
    aggb[(size_t)n * 128 + c] = f2bs(ax);
}

extern "C" void kernel_launch(void* const* d_in, const int* in_sizes, int n_in,
                              void* d_out, int out_size, void* d_ws, size_t ws_size,
                              hipStream_t stream) {
    const int*   z       = (const int*)d_in[0];
    const float* pos     = (const float*)d_in[1];
    const int*   eidx    = (const int*)d_in[2];
    const int*   src     = eidx;
    const int*   dst     = eidx + NE;
    const int*   batch   = (const int*)d_in[3];
    const float* emb     = (const float*)d_in[4];
    const float* mlp_w1  = (const float*)d_in[5];
    const float* mlp_b1  = (const float*)d_in[6];
    const float* mlp_w2  = (const float*)d_in[7];
    const float* mlp_b2  = (const float*)d_in[8];
    const float* conv_w1 = (const float*)d_in[9];
    const float* conv_w2 = (const float*)d_in[10];
    const float* conv_b2 = (const float*)d_in[11];
    const float* lin_w   = (const float*)d_in[12];
    const float* lin_b   = (const float*)d_in[13];
    const float* out1_w  = (const float*)d_in[14];
    const float* out1_b  = (const float*)d_in[15];
    const float* out2_w  = (const float*)d_in[16];
    const float* out2_b  = (const float*)d_in[17];
    float* out = (float*)d_out;

    char* wp = (char*)d_ws;
    auto alloc = [&](size_t bytes) {
        char* p = wp;
        wp += (bytes + 255) & ~(size_t)255;
        return p;
    };
    const int Mt = TBL + 2;
    int*    deg     = (int*)alloc(NN * 4);
    int*    row_ptr = (int*)alloc((NN + 1) * 4);
    int*    cursor  = (int*)alloc(NN * 4);
    int*    bsum    = (int*)alloc(128 * 4);
    float*  inv_cnt = (float*)alloc(NGRAPH * 4);
    int2*   csr     = (int2*)alloc((size_t)NE * 8);
    float*  A_tab   = (float*)alloc((size_t)Mt * GDIM * 4);
    float*  T1all   = (float*)alloc((size_t)LAYERS * Mt * 128 * 4);
    float*  T       = (float*)alloc((size_t)LAYERS * Mt * 128 * 4);
    unsigned int* Tb = (unsigned int*)alloc((size_t)LAYERS * (TBL + 1) * 128 * 4);
    float*  h       = (float*)alloc((size_t)NN * 128 * 4);
    unsigned short* aggb = (unsigned short*)alloc((size_t)NN * 128 * 2);
    unsigned short* xfb  = (unsigned short*)alloc((size_t)NN * 128 * 2);
    unsigned short* wbf  = (unsigned short*)alloc((size_t)26 * 16384 * 2);
    unsigned short* mlp_w2t  = wbf;
    unsigned short* conv_w1t = wbf + (size_t)6 * 16384;
    unsigned short* conv_w2t = wbf + (size_t)12 * 16384;
    unsigned short* lin_wt   = wbf + (size_t)18 * 16384;
    unsigned short* out1_wt  = wbf + (size_t)24 * 16384;
    unsigned short* out2_wt  = wbf + (size_t)25 * 16384;

    // merged prep: weight transposes + deg=0 + out=0 + table + h_init + inv_cnt
    WArgs wa;
    for (int l = 0; l < 6; l++) {
        wa.s[l]      = mlp_w2  + (size_t)l * 16384;  wa.d[l]      = mlp_w2t  + (size_t)l * 16384;
        wa.s[6 + l]  = conv_w1 + (size_t)l * 16384;  wa.d[6 + l]  = conv_w1t + (size_t)l * 16384;
        wa.s[12 + l] = conv_w2 + (size_t)l * 16384;  wa.d[12 + l] = conv_w2t + (size_t)l * 16384;
        wa.s[18 + l] = lin_w   + (size_t)l * 16384;  wa.d[18 + l] = lin_wt   + (size_t)l * 16384;
    }
    wa.s[24] = out1_w; wa.d[24] = out1_wt;
    wa.s[25] = out2_w; wa.d[25] = out2_wt;
    const int initN = NN + NGRAPH * 128 + Mt * GDIM + NN * 32 + NGRAPH;
    prep_a<<<PREP_WBLK + (initN + 255) / 256, 256, 0, stream>>>(wa, deg, out, A_tab, z,
                                                                emb, h, batch, inv_cnt);

    // graph structure
    deg_hist<<<(NE + 255) / 256, 256, 0, stream>>>(dst, deg);
    const int NB = (NN + 255) / 256;   // 79
    scan_a<<<NB, 256, 0, stream>>>(deg, row_ptr, bsum);
    scan_b<<<NB, 256, 0, stream>>>(bsum, row_ptr, cursor);
    csr_fill<<<(NE + 255) / 256, 256, 0, stream>>>(pos, src, dst, cursor, csr);

    // filter tables + layer-0 xfb
    const int gt32 = (Mt + 31) / 32;
    gemm_t<GDIM><<<dim3(gt32, LAYERS), 256, 0, stream>>>(
        A_tab, mlp_w1, mlp_b1, T1all, Mt, 1, 0, GDIM * 128, 128, Mt * 128);
    gemm_cs2<<<dim3(NN / 32, LAYERS + 1), 256, 0, stream>>>(
        T1all, mlp_w2t, mlp_b2, T, Mt,
        h, conv_w1t, xfb, NN);
    tquant<<<(LAYERS * (TBL + 1) * 128 + 255) / 256, 256, 0, stream>>>(T, Tb);

    // layers: pipelined edge gather then fused triple GEMM
    const int gn = NN / 16;   // 1250
    for (int l = 0; l < LAYERS; l++) {
        edge_agg<<<NN / 2, 256, 0, stream>>>(row_ptr, csr,
                                             Tb + (size_t)l * (TBL + 1) * 128, xfb, aggb);
        const unsigned short* w1n = (l + 1 < LAYERS) ? conv_w1t + (size_t)(l + 1) * 16384 : nullptr;
        gemm3<<<gn, 256, 0, stream>>>(aggb, conv_w2t + (size_t)l * 16384, conv_b2 + l * 128,
                                      lin_wt + (size_t)l * 16384, lin_b + l * 128,
                                      h, h, w1n, xfb);
    }

    // output head with fused per-graph mean
    gemm3h<<<gn, 256, 0, stream>>>(h, out1_wt, out1_b, out2_wt, out2_b,
                                   batch, inv_cnt, out);
}

// Round 12
// 524.181 us; speedup vs baseline: 1.0616x; 1.0616x over previous
//
#include <hip/hip_runtime.h>
#include <math.h>

#define NN 20000
#define NE 640000
#define GDIM 50
#define LAYERS 6
#define NGRAPH 64
#define TBL 2048
#define DMAXF 12.8f
#define G2_PAD 136   // LDS row stride in shorts (128 + 8 pad)

typedef __attribute__((ext_vector_type(8))) short short8;
typedef __attribute__((ext_vector_type(4))) float floatx4;

__device__ __forceinline__ float sspf(float x) {
    float sp = (x > 30.0f) ? x : log1pf(expf(x));
    return sp - 0.69314718055994530942f;
}

__device__ __forceinline__ unsigned short f2bs(float f) {
    union { float f; unsigned int i; } u; u.f = f;
    unsigned int r = u.i + 0x7fffu + ((u.i >> 16) & 1u);
    return (unsigned short)(r >> 16);
}

__device__ __forceinline__ float bs2f(unsigned int bits16) {
    union { unsigned int i; float f; } u; u.i = bits16 << 16;
    return u.f;
}

__device__ __forceinline__ short8 pack_bf16x8(float4 a, float4 b) {
    short8 o;
    o[0] = (short)f2bs(a.x); o[1] = (short)f2bs(a.y);
    o[2] = (short)f2bs(a.z); o[3] = (short)f2bs(a.w);
    o[4] = (short)f2bs(b.x); o[5] = (short)f2bs(b.y);
    o[6] = (short)f2bs(b.z); o[7] = (short)f2bs(b.w);
    return o;
}

// ---- merged prep: 26 weight transposes + deg=0 + out=0 + gaussian table +
//      h_init + per-graph inverse counts ----
struct WArgs { const float* s[26]; unsigned short* d[26]; };
#define PREP_WBLK 416            // 26 matrices x 16 tiles
__global__ void prep_a(WArgs a, int* __restrict__ deg, float* __restrict__ out,
                       float* __restrict__ A_tab, const int* __restrict__ z,
                       const float* __restrict__ emb, float* __restrict__ h,
                       const int* __restrict__ batch, float* __restrict__ inv_cnt) {
    __shared__ float tile[32][33];
    int b = blockIdx.x;
    if (b < PREP_WBLK) {
        int mz = b >> 4, sub = b & 15;
        int bx = (sub & 3) * 32, by = (sub >> 2) * 32;
        const float* Wm = a.s[mz];
        unsigned short* Wo = a.d[mz];
        int tx = threadIdx.x & 31, ty = threadIdx.x >> 5;
        for (int r = ty; r < 32; r += 8) tile[r][tx] = Wm[(by + r) * 128 + bx + tx];
        __syncthreads();
        for (int r = ty; r < 32; r += 8) Wo[(bx + r) * 128 + by + tx] = f2bs(tile[tx][r]);
        return;
    }
    int idx = (b - PREP_WBLK) * 256 + threadIdx.x;
    if (idx < NN) { deg[idx] = 0; return; }
    idx -= NN;
    if (idx < NGRAPH * 128) { out[idx] = 0.f; return; }
    idx -= NGRAPH * 128;
    if (idx < (TBL + 2) * GDIM) {
        int i = idx / GDIM, g = idx % GDIM;
        float v = 0.0f;
        if (i <= TBL) {
            float d = (float)i * (DMAXF / (float)TBL);
            float step = 10.0f / 49.0f;
            float off = (float)g * step;
            float coeff = -0.5f / (step * step);
            float dd = d - off;
            v = expf(coeff * dd * dd);
        }
        A_tab[idx] = v;
        return;
    }
    idx -= (TBL + 2) * GDIM;
    if (idx < NN * 32) {
        int n = idx >> 5, q = idx & 31;
        ((float4*)h)[n * 32 + q] = ((const float4*)emb)[(size_t)z[n] * 32 + q];
        return;
    }
    idx -= NN * 32;
    if (idx < NGRAPH) {
        int lo = 0, hi = NN;
        while (lo < hi) { int m = (lo + hi) >> 1; if (batch[m] < idx) lo = m + 1; else hi = m; }
        int lo2 = lo, hi2 = NN;
        while (lo2 < hi2) { int m = (lo2 + hi2) >> 1; if (batch[m] < idx + 1) lo2 = m + 1; else hi2 = m; }
        int cnt = lo2 - lo;
        inv_cnt[idx] = 1.0f / (float)(cnt > 0 ? cnt : 1);
    }
}

__global__ void deg_hist(const int* __restrict__ dst, int* __restrict__ deg) {
    int j = blockIdx.x * blockDim.x + threadIdx.x;
    if (j >= NE) return;
    atomicAdd(&deg[dst[j]], 1);
}

// hierarchical scan: local 256-scan + blocksums
__global__ void scan_a(const int* __restrict__ deg, int* __restrict__ row_ptr,
                       int* __restrict__ bsum) {
    __shared__ int sh[256];
    int b = blockIdx.x, t = threadIdx.x;
    int i = b * 256 + t;
    int v = (i < NN) ? deg[i] : 0;
    int x = v;
    sh[t] = x;
    __syncthreads();
    for (int off = 1; off < 256; off <<= 1) {
        int u = (t >= off) ? sh[t - off] : 0;
        __syncthreads();
        x += u;
        sh[t] = x;
        __syncthreads();
    }
    if (i <= NN) row_ptr[i] = x - v;   // local exclusive
    if (t == 255) bsum[b] = x;
}

// add block-prefix offsets; init cursor
__global__ void scan_b(const int* __restrict__ bsum, int* __restrict__ row_ptr,
                       int* __restrict__ cursor) {
    __shared__ int spref;
    int b = blockIdx.x, t = threadIdx.x;
    if (t < 64) {
        int s = 0;
        if (t < b) s += bsum[t];
        if (t + 64 < b) s += bsum[t + 64];
        for (int off = 32; off; off >>= 1) s += __shfl_down(s, off);
        if (t == 0) spref = s;
    }
    __syncthreads();
    int prefix = spref;
    int i = b * 256 + t;
    if (i < NN) {
        int v = row_ptr[i] + prefix;
        row_ptr[i] = v;
        cursor[i] = v;
    }
    if (b == 0 && t == 0) row_ptr[NN] = NE;
}

// CSR entry: int2{ (i0<<15)|src , bits(f) }   (cutoff C folded into table)
__global__ void csr_fill(const float* __restrict__ pos, const int* __restrict__ src,
                         const int* __restrict__ dst, int* __restrict__ cursor,
                         int2* __restrict__ csr) {
    int j = blockIdx.x * blockDim.x + threadIdx.x;
    if (j >= NE) return;
    int s = src[j], tno = dst[j];
    float dx = pos[3*s+0] - pos[3*tno+0];
    float dy = pos[3*s+1] - pos[3*tno+1];
    float dz = pos[3*s+2] - pos[3*tno+2];
    float d = sqrtf(dx*dx + dy*dy + dz*dz);
    float u = d * ((float)TBL / DMAXF);
    u = fminf(u, (float)(TBL + 1));
    int i0 = (int)u; if (i0 > TBL) i0 = TBL;
    float f = u - (float)i0;
    int p = atomicAdd(&cursor[tno], 1);
    csr[p] = make_int2((i0 << 15) | s, __float_as_int(f));
}

// fp32 tiled GEMM for the K=50 table stage only, batched over gridDim.y
template <int K>
__launch_bounds__(256, 2)
__global__ void gemm_t(const float* __restrict__ A, const float* __restrict__ W,
                       const float* __restrict__ bias, float* __restrict__ Y, int M,
                       int act, int aStride, int wStride, int bStride, int yStride) {
    constexpr int KP = (K + 3) & ~3;
    __shared__ __align__(16) float Ws[KP * 128];
    __shared__ __align__(16) float As[32 * KP];
    int l = blockIdx.y;
    A += (size_t)l * aStride;
    W += (size_t)l * wStride;
    if (bias) bias += (size_t)l * bStride;
    Y += (size_t)l * yStride;
    int t = threadIdx.x;
    int row0 = blockIdx.x * 32;
    for (int i = t; i < KP * 128; i += 256) Ws[i] = (i < K * 128) ? W[i] : 0.0f;
    for (int i = t; i < 32 * KP; i += 256) {
        int r = i / KP, k = i % KP;
        float v = 0.f;
        if (k < K && row0 + r < M) v = A[(size_t)(row0 + r) * K + k];
        As[r * KP + k] = v;
    }
    __syncthreads();
    int tx = t & 31, ty = t >> 5;
    int c0 = tx * 4, r0 = ty * 4;
    float acc[4][4] = {{0.f}};
    #pragma unroll 4
    for (int k = 0; k < KP; k += 4) {
        float4 a0 = *(const float4*)&As[(r0 + 0) * KP + k];
        float4 a1 = *(const float4*)&As[(r0 + 1) * KP + k];
        float4 a2 = *(const float4*)&As[(r0 + 2) * KP + k];
        float4 a3 = *(const float4*)&As[(r0 + 3) * KP + k];
        float4 w0 = *(const float4*)&Ws[(k + 0) * 128 + c0];
        float4 w1 = *(const float4*)&Ws[(k + 1) * 128 + c0];
        float4 w2 = *(const float4*)&Ws[(k + 2) * 128 + c0];
        float4 w3 = *(const float4*)&Ws[(k + 3) * 128 + c0];
        float av[4][4] = {{a0.x,a0.y,a0.z,a0.w},{a1.x,a1.y,a1.z,a1.w},
                          {a2.x,a2.y,a2.z,a2.w},{a3.x,a3.y,a3.z,a3.w}};
        float wv[4][4] = {{w0.x,w0.y,w0.z,w0.w},{w1.x,w1.y,w1.z,w1.w},
                          {w2.x,w2.y,w2.z,w2.w},{w3.x,w3.y,w3.z,w3.w}};
        #pragma unroll
        for (int i = 0; i < 4; i++)
            #pragma unroll
            for (int j = 0; j < 4; j++)
                #pragma unroll
                for (int q = 0; q < 4; q++)
                    acc[i][j] += av[i][q] * wv[q][j];
    }
    float b0 = 0.f, b1 = 0.f, b2 = 0.f, b3 = 0.f;
    if (bias) { b0 = bias[c0]; b1 = bias[c0+1]; b2 = bias[c0+2]; b3 = bias[c0+3]; }
    #pragma unroll
    for (int i = 0; i < 4; i++) {
        int r = row0 + r0 + i;
        if (r >= M) break;
        float4 v;
        v.x = acc[i][0] + b0; v.y = acc[i][1] + b1; v.z = acc[i][2] + b2; v.w = acc[i][3] + b3;
        if (act == 1) { v.x = sspf(v.x); v.y = sspf(v.y); v.z = sspf(v.z); v.w = sspf(v.w); }
        *(float4*)&Y[(size_t)r * 128 + c0] = v;
    }
}

// merged col-split MFMA GEMM: y<6 -> table layer y; y==6 -> layer-0 xfb job
__launch_bounds__(256)
__global__ void gemm_cs2(const float* __restrict__ A1, const unsigned short* __restrict__ W1t,
                         const float* __restrict__ bias1, float* __restrict__ Y1, int M1,
                         const float* __restrict__ A2, const unsigned short* __restrict__ W2t,
                         unsigned short* __restrict__ Yb2, int M2) {
    int y = blockIdx.y;
    const float* A; const unsigned short* Wt; const float* bias;
    float* Yf; unsigned short* Yb; int M;
    if (y < LAYERS) {
        M = M1;
        A = A1 + (size_t)y * M1 * 128;
        Wt = W1t + (size_t)y * 16384;
        bias = bias1 + (size_t)y * 128;
        Yf = Y1 + (size_t)y * M1 * 128;
        Yb = nullptr;
    } else {
        M = M2; A = A2; Wt = W2t; bias = nullptr; Yf = nullptr; Yb = Yb2;
    }
    int wv = threadIdx.x >> 6, lane = threadIdx.x & 63;
    int row0 = blockIdx.x * 32;
    if (row0 >= M) return;
    int lm = lane & 15, lk = (lane >> 4) * 8, orow = (lane >> 4) * 4;
    int r0 = row0 + lm;      r0 = (r0 < M) ? r0 : M - 1;
    int r1 = row0 + 16 + lm; r1 = (r1 < M) ? r1 : M - 1;
    const float* Ap0 = A + (size_t)r0 * 128;
    const float* Ap1 = A + (size_t)r1 * 128;
    short8 af0[4], af1[4];
    #pragma unroll
    for (int kq = 0; kq < 4; kq++) {
        af0[kq] = pack_bf16x8(*(const float4*)(Ap0 + kq * 32 + lk),
                              *(const float4*)(Ap0 + kq * 32 + lk + 4));
        af1[kq] = pack_bf16x8(*(const float4*)(Ap1 + kq * 32 + lk),
                              *(const float4*)(Ap1 + kq * 32 + lk + 4));
    }
    floatx4 acc[2][2];
    #pragma unroll
    for (int i = 0; i < 2; i++)
        #pragma unroll
        for (int j = 0; j < 2; j++) acc[i][j] = (floatx4){0, 0, 0, 0};
    const unsigned short* Wp = Wt + (size_t)(wv * 32) * 128;
    #pragma unroll
    for (int kq = 0; kq < 4; kq++) {
        #pragma unroll
        for (int ct = 0; ct < 2; ct++) {
            short8 bf = *(const short8*)(Wp + (size_t)(ct * 16 + lm) * 128 + kq * 32 + lk);
            acc[0][ct] = __builtin_amdgcn_mfma_f32_16x16x32_bf16(af0[kq], bf, acc[0][ct], 0, 0, 0);
            acc[1][ct] = __builtin_amdgcn_mfma_f32_16x16x32_bf16(af1[kq], bf, acc[1][ct], 0, 0, 0);
        }
    }
    #pragma unroll
    for (int tt = 0; tt < 2; tt++) {
        #pragma unroll
        for (int ct = 0; ct < 2; ct++) {
            int c = wv * 32 + ct * 16 + lm;
            float b = bias ? bias[c] : 0.f;
            #pragma unroll
            for (int r = 0; r < 4; r++) {
                int rr = row0 + tt * 16 + orow + r;
                if (rr >= M) continue;
                float v = acc[tt][ct][r] + b;
                if (Yf) Yf[(size_t)rr * 128 + c] = v;
                if (Yb) Yb[(size_t)rr * 128 + c] = f2bs(v);
            }
        }
    }
}

// fused triple GEMM, 16 rows/block, col-split waves; A input is bf16 (from edge_agg)
__launch_bounds__(256)
__global__ void gemm3(const unsigned short* __restrict__ aggb,
                      const unsigned short* __restrict__ W2t, const float* __restrict__ b2,
                      const unsigned short* __restrict__ W3t, const float* __restrict__ b3,
                      const float* __restrict__ resid, float* __restrict__ Yf,
                      const unsigned short* __restrict__ W1nt, unsigned short* __restrict__ xfb) {
    __shared__ unsigned short Ls[16 * G2_PAD];
    int wv = threadIdx.x >> 6, lane = threadIdx.x & 63;
    int row0 = blockIdx.x * 16;
    int lm = lane & 15, lk = (lane >> 4) * 8, orow = (lane >> 4) * 4;
    int cw = wv * 32;
    // prefetch residual rows early (consumed at phase-2 epilogue)
    float rpre[2][4];
    #pragma unroll
    for (int ct = 0; ct < 2; ct++)
        #pragma unroll
        for (int r = 0; r < 4; r++)
            rpre[ct][r] = resid[(size_t)(row0 + orow + r) * 128 + cw + ct * 16 + lm];
    // ---- phase 1: t1 = ssp(aggb @ W2t^T + b2) -> LDS ----
    {
        const unsigned short* Ap = aggb + (size_t)(row0 + lm) * 128;
        short8 af[4];
        #pragma unroll
        for (int kq = 0; kq < 4; kq++)
            af[kq] = *(const short8*)(Ap + kq * 32 + lk);
        floatx4 acc[2];
        acc[0] = (floatx4){0, 0, 0, 0}; acc[1] = (floatx4){0, 0, 0, 0};
        const unsigned short* Wp = W2t + (size_t)cw * 128;
        #pragma unroll
        for (int kq = 0; kq < 4; kq++) {
            #pragma unroll
            for (int ct = 0; ct < 2; ct++) {
                short8 bf = *(const short8*)(Wp + (size_t)(ct * 16 + lm) * 128 + kq * 32 + lk);
                acc[ct] = __builtin_amdgcn_mfma_f32_16x16x32_bf16(af[kq], bf, acc[ct], 0, 0, 0);
            }
        }
        #pragma unroll
        for (int ct = 0; ct < 2; ct++) {
            int c = cw + ct * 16 + lm;
            float b = b2[c];
            #pragma unroll
            for (int r = 0; r < 4; r++)
                Ls[(orow + r) * G2_PAD + c] = f2bs(sspf(acc[ct][r] + b));
        }
    }
    __syncthreads();
    // ---- phase 2: h_new = t1 @ W3t^T + b3 + resid -> Yf ----
    float vout[2][4];
    {
        short8 a2[4];
        #pragma unroll
        for (int kq = 0; kq < 4; kq++)
            a2[kq] = *(const short8*)&Ls[lm * G2_PAD + kq * 32 + lk];
        floatx4 acc[2];
        acc[0] = (floatx4){0, 0, 0, 0}; acc[1] = (floatx4){0, 0, 0, 0};
        const unsigned short* Wp = W3t + (size_t)cw * 128;
        #pragma unroll
        for (int kq = 0; kq < 4; kq++) {
            #pragma unroll
            for (int ct = 0; ct < 2; ct++) {
                short8 bf = *(const short8*)(Wp + (size_t)(ct * 16 + lm) * 128 + kq * 32 + lk);
                acc[ct] = __builtin_amdgcn_mfma_f32_16x16x32_bf16(a2[kq], bf, acc[ct], 0, 0, 0);
            }
        }
        #pragma unroll
        for (int ct = 0; ct < 2; ct++) {
            int c = cw + ct * 16 + lm;
            float b = b3[c];
            #pragma unroll
            for (int r = 0; r < 4; r++) {
                int rr = row0 + orow + r;
                float v = acc[ct][r] + b + rpre[ct][r];
                Yf[(size_t)rr * 128 + c] = v;
                vout[ct][r] = v;
            }
        }
    }
    if (!W1nt) return;
    __syncthreads();
    #pragma unroll
    for (int ct = 0; ct < 2; ct++) {
        int c = cw + ct * 16 + lm;
        #pragma unroll
        for (int r = 0; r < 4; r++)
            Ls[(orow + r) * G2_PAD + c] = f2bs(vout[ct][r]);
    }
    __syncthreads();
    // ---- phase 3: xfb = bf16(h_new @ W1nt^T) ----
    {
        short8 a3[4];
        #pragma unroll
        for (int kq = 0; kq < 4; kq++)
            a3[kq] = *(const short8*)&Ls[lm * G2_PAD + kq * 32 + lk];
        floatx4 acc[2];
        acc[0] = (floatx4){0, 0, 0, 0}; acc[1] = (floatx4){0, 0, 0, 0};
        const unsigned short* Wp = W1nt + (size_t)cw * 128;
        #pragma unroll
        for (int kq = 0; kq < 4; kq++) {
            #pragma unroll
            for (int ct = 0; ct < 2; ct++) {
                short8 bf = *(const short8*)(Wp + (size_t)(ct * 16 + lm) * 128 + kq * 32 + lk);
                acc[ct] = __builtin_amdgcn_mfma_f32_16x16x32_bf16(a3[kq], bf, acc[ct], 0, 0, 0);
            }
        }
        #pragma unroll
        for (int ct = 0; ct < 2; ct++) {
            int c = cw + ct * 16 + lm;
            #pragma unroll
            for (int r = 0; r < 4; r++)
                xfb[(size_t)(row0 + orow + r) * 128 + c] = f2bs(acc[ct][r]);
        }
    }
}

// head: out[g] += mean-scaled ssp(h @ out1 + b1) @ out2 + b2  (fused readout)
__launch_bounds__(256)
__global__ void gemm3h(const float* __restrict__ A,
                       const unsigned short* __restrict__ W2t, const float* __restrict__ b2,
                       const unsigned short* __restrict__ W3t, const float* __restrict__ b3,
                       const int* __restrict__ batch, const float* __restrict__ inv_cnt,
                       float* __restrict__ out) {
    __shared__ unsigned short Ls[16 * G2_PAD];
    int wv = threadIdx.x >> 6, lane = threadIdx.x & 63;
    int row0 = blockIdx.x * 16;
    int lm = lane & 15, lk = (lane >> 4) * 8, orow = (lane >> 4) * 4;
    int cw = wv * 32;
    {
        const float* Ap = A + (size_t)(row0 + lm) * 128;
        short8 af[4];
        #pragma unroll
        for (int kq = 0; kq < 4; kq++)
            af[kq] = pack_bf16x8(*(const float4*)(Ap + kq * 32 + lk),
                                 *(const float4*)(Ap + kq * 32 + lk + 4));
        floatx4 acc[2];
        acc[0] = (floatx4){0, 0, 0, 0}; acc[1] = (floatx4){0, 0, 0, 0};
        const unsigned short* Wp = W2t + (size_t)cw * 128;
        #pragma unroll
        for (int kq = 0; kq < 4; kq++) {
            #pragma unroll
            for (int ct = 0; ct < 2; ct++) {
                short8 bf = *(const short8*)(Wp + (size_t)(ct * 16 + lm) * 128 + kq * 32 + lk);
                acc[ct] = __builtin_amdgcn_mfma_f32_16x16x32_bf16(af[kq], bf, acc[ct], 0, 0, 0);
            }
        }
        #pragma unroll
        for (int ct = 0; ct < 2; ct++) {
            int c = cw + ct * 16 + lm;
            float b = b2[c];
            #pragma unroll
            for (int r = 0; r < 4; r++)
                Ls[(orow + r) * G2_PAD + c] = f2bs(sspf(acc[ct][r] + b));
        }
    }
    __syncthreads();
    float vout[2][4];
    {
        short8 a2[4];
        #pragma unroll
        for (int kq = 0; kq < 4; kq++)
            a2[kq] = *(const short8*)&Ls[lm * G2_PAD + kq * 32 + lk];
        floatx4 acc[2];
        acc[0] = (floatx4){0, 0, 0, 0}; acc[1] = (floatx4){0, 0, 0, 0};
        const unsigned short* Wp = W3t + (size_t)cw * 128;
        #pragma unroll
        for (int kq = 0; kq < 4; kq++) {
            #pragma unroll
            for (int ct = 0; ct < 2; ct++) {
                short8 bf = *(const short8*)(Wp + (size_t)(ct * 16 + lm) * 128 + kq * 32 + lk);
                acc[ct] = __builtin_amdgcn_mfma_f32_16x16x32_bf16(a2[kq], bf, acc[ct], 0, 0, 0);
            }
        }
        #pragma unroll
        for (int ct = 0; ct < 2; ct++) {
            int c = cw + ct * 16 + lm;
            float b = b3[c];
            #pragma unroll
            for (int r = 0; r < 4; r++)
                vout[ct][r] = acc[ct][r] + b;
        }
    }
    // fused mean readout
    int g0  = __builtin_amdgcn_readfirstlane(batch[row0]);
    int g15 = __builtin_amdgcn_readfirstlane(batch[row0 + 15]);
    if (g0 == g15) {
        float inv = inv_cnt[g0];
        #pragma unroll
        for (int ct = 0; ct < 2; ct++) {
            float s = vout[ct][0] + vout[ct][1] + vout[ct][2] + vout[ct][3];
            s += __shfl_xor(s, 16);
            s += __shfl_xor(s, 32);
            if (lane < 16)
                atomicAdd(&out[g0 * 128 + cw + ct * 16 + lm], s * inv);
        }
    } else {
        #pragma unroll
        for (int ct = 0; ct < 2; ct++) {
            int c = cw + ct * 16 + lm;
            #pragma unroll
            for (int r = 0; r < 4; r++) {
                int g = batch[row0 + orow + r];
                atomicAdd(&out[g * 128 + c], vout[ct][r] * inv_cnt[g]);
            }
        }
    }
}

// fold cutoff C(d) into table; one uint per channel: (dW<<16)|W
__global__ void tquant(const float* __restrict__ T, unsigned int* __restrict__ Tb) {
    int idx = blockIdx.x * blockDim.x + threadIdx.x;
    const int total = LAYERS * (TBL + 1) * 128;
    if (idx >= total) return;
    int c = idx & 127;
    int li = idx >> 7;
    int i = li % (TBL + 1);
    int l = li / (TBL + 1);
    float d0 = (float)i * (DMAXF / (float)TBL);
    float d1 = (float)(i + 1) * (DMAXF / (float)TBL);
    float C0 = 0.5f * (cosf(d0 * 0.31415926535897931f) + 1.0f);
    float C1 = 0.5f * (cosf(d1 * 0.31415926535897931f) + 1.0f);
    const float* row = T + ((size_t)l * (TBL + 2) + i) * 128 + c;
    float w = row[0] * C0;
    float nw = row[128] * C1;
    Tb[idx] = ((unsigned)f2bs(nw - w) << 16) | f2bs(w);
}

// 2 waves per node (64-channel halves); scalar CSR loads; 16x unroll; bf16 out
__launch_bounds__(256)
__global__ void edge_agg(const int* __restrict__ row_ptr, const int2* __restrict__ csr,
                         const unsigned int* __restrict__ Tb,
                         const unsigned short* __restrict__ xfb,
                         unsigned short* __restrict__ aggb) {
    int wv = __builtin_amdgcn_readfirstlane(threadIdx.x >> 6);
    int lane = threadIdx.x & 63;
    int n = blockIdx.x * 2 + (wv >> 1);
    int c = (wv & 1) * 64 + lane;
    int e0 = row_ptr[n], e1 = row_ptr[n + 1];
    float ax = 0.f;
    int e = e0;
    for (; e + 16 <= e1; e += 16) {
        unsigned int px[16]; float ff[16];
        #pragma unroll
        for (int q = 0; q < 16; q++) {
            int2 ed = csr[e + q];
            px[q] = (unsigned int)__builtin_amdgcn_readfirstlane(ed.x);
            ff[q] = __int_as_float(__builtin_amdgcn_readfirstlane(ed.y));
        }
        unsigned int tw[16]; unsigned short xv[16];
        #pragma unroll
        for (int q = 0; q < 16; q++) {
            tw[q] = Tb[(px[q] >> 15) * 128 + c];
            xv[q] = xfb[(size_t)(px[q] & 0x7fffu) * 128 + c];
        }
        #pragma unroll
        for (int q = 0; q < 16; q++) {
            float w = bs2f(tw[q] & 0xffffu), dw = bs2f(tw[q] >> 16);
            float x = bs2f((unsigned int)xv[q]);
            ax = fmaf(x, fmaf(ff[q], dw, w), ax);
        }
    }
    for (; e + 4 <= e1; e += 4) {
        unsigned int px[4]; float ff[4];
        #pragma unroll
        for (int q = 0; q < 4; q++) {
            int2 ed = csr[e + q];
            px[q] = (unsigned int)__builtin_amdgcn_readfirstlane(ed.x);
            ff[q] = __int_as_float(__builtin_amdgcn_readfirstlane(ed.y));
        }
        unsigned int tw[4]; unsigned short xv[4];
        #pragma unroll
        for (int q = 0; q < 4; q++) {
            tw[q] = Tb[(px[q] >> 15) * 128 + c];
            xv[q] = xfb[(size_t)(px[q] & 0x7fffu) * 128 + c];
        }
        #pragma unroll
        for (int q = 0; q < 4; q++) {
            float w = bs2f(tw[q] & 0xffffu), dw = bs2f(tw[q] >> 16);
            float x = bs2f((unsigned int)xv[q]);
            ax = fmaf(x, fmaf(ff[q], dw, w), ax);
        }
    }
    for (; e < e1; e++) {
        int2 ed = csr[e];
        unsigned int px = (unsigned int)__builtin_amdgcn_readfirstlane(ed.x);
        float f = __int_as_float(__builtin_amdgcn_readfirstlane(ed.y));
        unsigned int tw = Tb[(px >> 15) * 128 + c];
        unsigned short xv = xfb[(size_t)(px & 0x7fffu) * 128 + c];
        float w = bs2f(tw & 0xffffu), dw = bs2f(tw >> 16);
        float x = bs2f((unsigned int)xv);
        ax = fmaf(x, fmaf(f, dw, w), ax);
    }
    aggb[(size_t)n * 128 + c] = f2bs(ax);
}

extern "C" void kernel_launch(void* const* d_in, const int* in_sizes, int n_in,
                              void* d_out, int out_size, void* d_ws, size_t ws_size,
                              hipStream_t stream) {
    const int*   z       = (const int*)d_in[0];
    const float* pos     = (const float*)d_in[1];
    const int*   eidx    = (const int*)d_in[2];
    const int*   src     = eidx;
    const int*   dst     = eidx + NE;
    const int*   batch   = (const int*)d_in[3];
    const float* emb     = (const float*)d_in[4];
    const float* mlp_w1  = (const float*)d_in[5];
    const float* mlp_b1  = (const float*)d_in[6];
    const float* mlp_w2  = (const float*)d_in[7];
    const float* mlp_b2  = (const float*)d_in[8];
    const float* conv_w1 = (const float*)d_in[9];
    const float* conv_w2 = (const float*)d_in[10];
    const float* conv_b2 = (const float*)d_in[11];
    const float* lin_w   = (const float*)d_in[12];
    const float* lin_b   = (const float*)d_in[13];
    const float* out1_w  = (const float*)d_in[14];
    const float* out1_b  = (const float*)d_in[15];
    const float* out2_w  = (const float*)d_in[16];
    const float* out2_b  = (const float*)d_in[17];
    float* out = (float*)d_out;

    char* wp = (char*)d_ws;
    auto alloc = [&](size_t bytes) {
        char* p = wp;
        wp += (bytes + 255) & ~(size_t)255;
        return p;
    };
    const int Mt = TBL + 2;
    int*    deg     = (int*)alloc(NN * 4);
    int*    row_ptr = (int*)alloc((NN + 1) * 4);
    int*    cursor  = (int*)alloc(NN * 4);
    int*    bsum    = (int*)alloc(128 * 4);
    float*  inv_cnt = (float*)alloc(NGRAPH * 4);
    int2*   csr     = (int2*)alloc((size_t)NE * 8);
    float*  A_tab   = (float*)alloc((size_t)Mt * GDIM * 4);
    float*  T1all   = (float*)alloc((size_t)LAYERS * Mt * 128 * 4);
    float*  T       = (float*)alloc((size_t)LAYERS * Mt * 128 * 4);
    unsigned int* Tb = (unsigned int*)alloc((size_t)LAYERS * (TBL + 1) * 128 * 4);
    float*  h       = (float*)alloc((size_t)NN * 128 * 4);
    unsigned short* aggb = (unsigned short*)alloc((size_t)NN * 128 * 2);
    unsigned short* xfb  = (unsigned short*)alloc((size_t)NN * 128 * 2);
    unsigned short* wbf  = (unsigned short*)alloc((size_t)26 * 16384 * 2);
    unsigned short* mlp_w2t  = wbf;
    unsigned short* conv_w1t = wbf + (size_t)6 * 16384;
    unsigned short* conv_w2t = wbf + (size_t)12 * 16384;
    unsigned short* lin_wt   = wbf + (size_t)18 * 16384;
    unsigned short* out1_wt  = wbf + (size_t)24 * 16384;
    unsigned short* out2_wt  = wbf + (size_t)25 * 16384;

    // merged prep: weight transposes + deg=0 + out=0 + table + h_init + inv_cnt
    WArgs wa;
    for (int l = 0; l < 6; l++) {
        wa.s[l]      = mlp_w2  + (size_t)l * 16384;  wa.d[l]      = mlp_w2t  + (size_t)l * 16384;
        wa.s[6 + l]  = conv_w1 + (size_t)l * 16384;  wa.d[6 + l]  = conv_w1t + (size_t)l * 16384;
        wa.s[12 + l] = conv_w2 + (size_t)l * 16384;  wa.d[12 + l] = conv_w2t + (size_t)l * 16384;
        wa.s[18 + l] = lin_w   + (size_t)l * 16384;  wa.d[18 + l] = lin_wt   + (size_t)l * 16384;
    }
    wa.s[24] = out1_w; wa.d[24] = out1_wt;
    wa.s[25] = out2_w; wa.d[25] = out2_wt;
    const int initN = NN + NGRAPH * 128 + Mt * GDIM + NN * 32 + NGRAPH;
    prep_a<<<PREP_WBLK + (initN + 255) / 256, 256, 0, stream>>>(wa, deg, out, A_tab, z,
                                                                emb, h, batch, inv_cnt);

    // graph structure
    deg_hist<<<(NE + 255) / 256, 256, 0, stream>>>(dst, deg);
    const int NB = (NN + 255) / 256;   // 79
    scan_a<<<NB, 256, 0, stream>>>(deg, row_ptr, bsum);
    scan_b<<<NB, 256, 0, stream>>>(bsum, row_ptr, cursor);
    csr_fill<<<(NE + 255) / 256, 256, 0, stream>>>(pos, src, dst, cursor, csr);

    // filter tables + layer-0 xfb
    const int gt32 = (Mt + 31) / 32;
    gemm_t<GDIM><<<dim3(gt32, LAYERS), 256, 0, stream>>>(
        A_tab, mlp_w1, mlp_b1, T1all, Mt, 1, 0, GDIM * 128, 128, Mt * 128);
    gemm_cs2<<<dim3(NN / 32, LAYERS + 1), 256, 0, stream>>>(
        T1all, mlp_w2t, mlp_b2, T, Mt,
        h, conv_w1t, xfb, NN);
    tquant<<<(LAYERS * (TBL + 1) * 128 + 255) / 256, 256, 0, stream>>>(T, Tb);

    // layers: edge gather (2 waves/node, 16x unroll) then fused triple GEMM
    const int gn = NN / 16;   // 1250
    for (int l = 0; l < LAYERS; l++) {
        edge_agg<<<NN / 2, 256, 0, stream>>>(row_ptr, csr,
                                             Tb + (size_t)l * (TBL + 1) * 128, xfb, aggb);
        const unsigned short* w1n = (l + 1 < LAYERS) ? conv_w1t + (size_t)(l + 1) * 16384 : nullptr;
        gemm3<<<gn, 256, 0, stream>>>(aggb, conv_w2t + (size_t)l * 16384, conv_b2 + l * 128,
                                      lin_wt + (size_t)l * 16384, lin_b + l * 128,
                                      h, h, w1n, xfb);
    }

    // output head with fused per-graph mean
    gemm3h<<<gn, 256, 0, stream>>>(h, out1_wt, out1_b, out2_wt, out2_b,
                                   batch, inv_cnt, out);
}